// Round 14
// baseline (595.775 us; speedup 1.0000x reference)
//
#include <hip/hip_runtime.h>
#include <hip/hip_bf16.h>
#include <stdint.h>

#define LVLS 16
#define TSZ  524288          // hash table size per level (2^19)
#define TMASK 0x7FFFFu
#define NPTS 524288
#define P1 2654435761u
#define P2 805459861u
#define P3 3674653429u

// floor(16 * 1.5^l), hardcoded
__constant__ float RES_TAB[16] = {
    16.f, 24.f, 36.f, 54.f, 81.f, 121.f, 182.f, 273.f,
    410.f, 615.f, 922.f, 1383.f, 2075.f, 3113.f, 4670.f, 7006.f};

using f16x8 = __attribute__((ext_vector_type(8))) _Float16;
using f16x4 = __attribute__((ext_vector_type(4))) _Float16;
using f32x4 = __attribute__((ext_vector_type(4))) float;
using u32x8 = __attribute__((ext_vector_type(8))) uint32_t;

union PackF16 { uint32_t u; _Float16 h[2]; };

struct WPtrs { const float* p[11]; };

// ---------------------------------------------------------------------------
// Kernel B: XCD-pinned table build (r12 vectorized main part, perf-neutral,
// kept) + NEW weight swizzle for the 16x16x16 LDS-free MLP chain:
//   tile t (272 total), lane: f16x4 = { W[kc*16+(lane>>4)*4+j][ct*16+(lane&15)] }
// Segment map (tile base, KC=K/16, N): ws_in 0(2,64) | ws_hid 8,24,40(4,64) |
// ws_out 56 | wd_* +72 | w1_in 144(8,64) | w1_hid 176(4,64) | w1_out 192(4,128)
// | w2_in 224(8,64) | w2_hid 256(4,64). Total 272 tiles = 139264 B (same buf).
// ---------------------------------------------------------------------------
__global__ void k_build(const float* __restrict__ ts, const float* __restrict__ td,
                        const float* __restrict__ tptr, uint2* __restrict__ Tc,
                        WPtrs wp, _Float16* __restrict__ wdst) {
    int B = blockIdx.x;
    int tid = threadIdx.x;
    if (B < 10240) {
        int c = B & 7, j = B >> 3;            // j 0..1279 within class
        int l, e;
        if (j < 256) {                        // coarse: half level per class
            l = c >> 1;
            e = (c & 1) * 262144 + j * 1024 + tid * 4;
        } else if (j < 768) {                 // shared: full level (dup per pair)
            l = 12 + (c >> 1);
            e = (j - 256) * 1024 + tid * 4;
        } else {                              // exclusive: full level, LAST
            l = 4 + c;
            e = (j - 768) * 1024 + tid * 4;
        }
        size_t base = (size_t)l * TSZ + (size_t)e;
        const float4* ts4 = (const float4*)ts;
        float4 s01 = ts4[base >> 1];
        float4 s23 = ts4[(base >> 1) + 1];
        float res = RES_TAB[l];
        float tv  = tptr[0];
        float pt  = tv * res;
        float fpt = floorf(pt);
        float ft  = pt - fpt;
        uint32_t ut = (uint32_t)(int)fpt;
        uint32_t h0 = (ut * P3) & TMASK;
        uint32_t h1 = ((ut + 1u) * P3) & TMASK;
        const float4* td4 = (const float4*)((const float2*)td + (size_t)l * TSZ);
        uint32_t b0 = ((uint32_t)e ^ h0) & ~3u, s0 = h0 & 3u;
        uint32_t b1 = ((uint32_t)e ^ h1) & ~3u, s1 = h1 & 3u;
        float4 A0 = td4[b0 >> 1], A1 = td4[(b0 >> 1) + 1];
        float4 B0 = td4[b1 >> 1], B1 = td4[(b1 >> 1) + 1];
        float2 a[4] = {{A0.x,A0.y},{A0.z,A0.w},{A1.x,A1.y},{A1.z,A1.w}};
        float2 b[4] = {{B0.x,B0.y},{B0.z,B0.w},{B1.x,B1.y},{B1.z,B1.w}};
        float2 sv[4] = {{s01.x,s01.y},{s01.z,s01.w},{s23.x,s23.y},{s23.z,s23.w}};
        float2 ap[4], bp[4];
        switch (s0) {
        case 0: ap[0]=a[0]; ap[1]=a[1]; ap[2]=a[2]; ap[3]=a[3]; break;
        case 1: ap[0]=a[1]; ap[1]=a[0]; ap[2]=a[3]; ap[3]=a[2]; break;
        case 2: ap[0]=a[2]; ap[1]=a[3]; ap[2]=a[0]; ap[3]=a[1]; break;
        default:ap[0]=a[3]; ap[1]=a[2]; ap[2]=a[1]; ap[3]=a[0]; break;
        }
        switch (s1) {
        case 0: bp[0]=b[0]; bp[1]=b[1]; bp[2]=b[2]; bp[3]=b[3]; break;
        case 1: bp[0]=b[1]; bp[1]=b[0]; bp[2]=b[3]; bp[3]=b[2]; break;
        case 2: bp[0]=b[2]; bp[1]=b[3]; bp[2]=b[0]; bp[3]=b[1]; break;
        default:bp[0]=b[3]; bp[1]=b[2]; bp[2]=b[1]; bp[3]=b[0]; break;
        }
        uint32_t ow[8];
#pragma unroll
        for (int jj = 0; jj < 4; jj++) {
            PackF16 o0, o1;
            o0.h[0] = (_Float16)sv[jj].x; o0.h[1] = (_Float16)sv[jj].y;
            o1.h[0] = (_Float16)((1.f - ft) * ap[jj].x + ft * bp[jj].x);
            o1.h[1] = (_Float16)((1.f - ft) * ap[jj].y + ft * bp[jj].y);
            ow[jj*2]   = o0.u;
            ow[jj*2+1] = o1.u;
        }
        uint4* dst = (uint4*)(Tc + base);
        dst[0] = make_uint4(ow[0], ow[1], ow[2], ow[3]);
        dst[1] = make_uint4(ow[4], ow[5], ow[6], ow[7]);
    } else {
        // ---- weight swizzle: 16x16x16 A-fragment layout ----
        int id = (B - 10240) * 256 + tid;
        if (id >= 17408) return;              // 272 tiles x 64 lanes
        int lane = id & 63;
        int t    = id >> 6;
        const int TB[12]   = {0,8,56,72,80,128,144,176,192,224,256,272};
        const int KCt[11]  = {2,4,4, 2,4,4, 8,4,4, 8,4};
        const int NNt[11]  = {64,64,64, 64,64,64, 64,64,128, 64,64};
        const int PSELt[11]= {0,1,2, 3,4,5, 6,7,8, 9,10};
        int s = 0;
        while (t >= TB[s+1]) s++;
        int local = t - TB[s];
        const float* src = wp.p[PSELt[s]];
        if (s == 1 || s == 4) { src += (local >> 4) * 4096; local &= 15; }
        int KC = KCt[s], N = NNt[s];
        int ct = local / KC, kc = local - ct * KC;
        int k0 = kc*16 + (lane >> 4)*4;
        int n  = ct*16 + (lane & 15);
        _Float16* d = wdst + ((size_t)t*64 + lane)*4;
#pragma unroll
        for (int jj = 0; jj < 4; jj++)
            d[jj] = (_Float16)src[(k0 + jj) * N + n];
    }
}

// ---------------------------------------------------------------------------
// Kernel E: hash-grid encode — r6 version verbatim (227 us, at its
// VMEM-issue roofline, reproduced 4x). Unchanged.
// ---------------------------------------------------------------------------
__device__ __forceinline__ void gather1(const uint2* __restrict__ tcl,
                                        float px, float py, float pz,
                                        u32x8& va, u32x8& vb,
                                        float& wx, float& wy, float& wz) {
    float fx = floorf(px), fy = floorf(py), fz = floorf(pz);
    wx = px - fx; wy = py - fy; wz = pz - fz;
    uint32_t ux = (uint32_t)(int)fx, uy = (uint32_t)(int)fy, uz = (uint32_t)(int)fz;
    uint32_t hx0 = ux,     hx1 = ux + 1u;
    uint32_t hy0 = uy*P1,  hy1 = (uy+1u)*P1;
    uint32_t hz0 = uz*P2,  hz1 = (uz+1u)*P2;
#pragma unroll
    for (int cc = 0; cc < 8; cc++) {
        uint32_t idx = (((cc&1)?hx1:hx0) ^ ((cc&2)?hy1:hy0) ^ ((cc&4)?hz1:hz0)) & TMASK;
        uint2 t = tcl[idx];
        if (cc < 4) { va[(cc&3)*2+0] = t.x; va[(cc&3)*2+1] = t.y; }
        else        { vb[(cc&3)*2+0] = t.x; vb[(cc&3)*2+1] = t.y; }
    }
}

__device__ __forceinline__ void consume1(const u32x8& va, const u32x8& vb,
                                         float wx, float wy, float wz,
                                         uint32_t* __restrict__ es,
                                         uint32_t* __restrict__ ed, int p) {
    float wxa[2] = {1.f-wx, wx}, wya[2] = {1.f-wy, wy}, wza[2] = {1.f-wz, wz};
    float sA0 = 0.f, sA1 = 0.f, sD0 = 0.f, sD1 = 0.f;
#pragma unroll
    for (int cc = 0; cc < 8; cc++) {
        float w = wxa[cc&1] * wya[(cc>>1)&1] * wza[cc>>2];
        PackF16 s, d;
        s.u = (cc<4) ? va[(cc&3)*2+0] : vb[(cc&3)*2+0];
        d.u = (cc<4) ? va[(cc&3)*2+1] : vb[(cc&3)*2+1];
        sA0 += w*(float)s.h[0]; sA1 += w*(float)s.h[1];
        sD0 += w*(float)d.h[0]; sD1 += w*(float)d.h[1];
    }
    PackF16 o;
    o.h[0] = (_Float16)sA0; o.h[1] = (_Float16)sA1; es[p] = o.u;
    o.h[0] = (_Float16)sD0; o.h[1] = (_Float16)sD1; ed[p] = o.u;
}

#define MEMFENCE asm volatile("" ::: "memory")
#define PIN(a,b,c,d) asm volatile("" : "+v"(a), "+v"(b), "+v"(c), "+v"(d))

__launch_bounds__(256, 4)
__global__ void k_encode(const float* __restrict__ x,
                         const uint2* __restrict__ Tc,
                         uint32_t* __restrict__ EncS, uint32_t* __restrict__ EncD) {
    int tid = threadIdx.x;
    int c   = blockIdx.x & 7;                // XCD class
    int b   = blockIdx.x >> 3;               // 0..511 within class
    int l, pb, stride;
    if (b < 256) {
        l = 4 + c;
        pb = b * 256 + tid;
        stride = 65536;
    } else if (b < 384) {
        l = 12 + (c >> 1);
        pb = (c & 1) * 262144 + (b - 256) * 256 + tid;
        stride = 32768;
    } else {
        l = c >> 1;
        pb = (c & 1) * 262144 + (b - 384) * 256 + tid;
        stride = 32768;
    }
    const uint2* tcl = Tc + (size_t)l * TSZ;
    uint32_t* es = EncS + (size_t)l * NPTS;
    uint32_t* ed = EncD + (size_t)l * NPTS;
    float res = RES_TAB[l];

    float PX[8], PY[8], PZ[8];
#pragma unroll
    for (int i = 0; i < 8; i++) {
        int p = pb + i * stride;
        PX[i] = x[p*3+0]*res; PY[i] = x[p*3+1]*res; PZ[i] = x[p*3+2]*res;
    }

    u32x8 A0, A1, A2, A3, B0, B1, B2, B3;
    float wA0x, wA0y, wA0z, wA1x, wA1y, wA1z;
    float wB0x, wB0y, wB0z, wB1x, wB1y, wB1z;

    gather1(tcl, PX[0], PY[0], PZ[0], A0, A1, wA0x, wA0y, wA0z);
    gather1(tcl, PX[1], PY[1], PZ[1], A2, A3, wA1x, wA1y, wA1z);
    gather1(tcl, PX[2], PY[2], PZ[2], B0, B1, wB0x, wB0y, wB0z);
    gather1(tcl, PX[3], PY[3], PZ[3], B2, B3, wB1x, wB1y, wB1z);
    MEMFENCE;
    PIN(A0, A1, A2, A3);
    consume1(A0, A1, wA0x, wA0y, wA0z, es, ed, pb + 0*stride);
    consume1(A2, A3, wA1x, wA1y, wA1z, es, ed, pb + 1*stride);
    gather1(tcl, PX[4], PY[4], PZ[4], A0, A1, wA0x, wA0y, wA0z);
    gather1(tcl, PX[5], PY[5], PZ[5], A2, A3, wA1x, wA1y, wA1z);
    MEMFENCE;
    PIN(B0, B1, B2, B3);
    consume1(B0, B1, wB0x, wB0y, wB0z, es, ed, pb + 2*stride);
    consume1(B2, B3, wB1x, wB1y, wB1z, es, ed, pb + 3*stride);
    gather1(tcl, PX[6], PY[6], PZ[6], B0, B1, wB0x, wB0y, wB0z);
    gather1(tcl, PX[7], PY[7], PZ[7], B2, B3, wB1x, wB1y, wB1z);
    MEMFENCE;
    PIN(A0, A1, A2, A3);
    consume1(A0, A1, wA0x, wA0y, wA0z, es, ed, pb + 4*stride);
    consume1(A2, A3, wA1x, wA1y, wA1z, es, ed, pb + 5*stride);
    PIN(B0, B1, B2, B3);
    consume1(B0, B1, wB0x, wB0y, wB0z, es, ed, pb + 6*stride);
    consume1(B2, B3, wB1x, wB1y, wB1z, es, ed, pb + 7*stride);
}

// ---------------------------------------------------------------------------
// Kernel M: LDS-FREE MLP via swapped-operand 16x16x16 MFMA chain.
// Identity: Y^T = W^T * X^T with A=W-frag (lane m': out-feat ct*16+(lane&15),
// k=(lane>>4)*4+j), B=X-frag (lane: point rt*16+m, same k map). D layout
// (col=lane&15, row=(lane>>4)*4+i, m89-verified, dtype-independent) gives
// lane (m,q): Y[point rt*16+m][feat ct*16+q*4+i] — which IS the next layer's
// B-fragment (kc=ct, j=i) after relu+pack. Layer hand-off = 8 packs in
// registers. No LDS, no barriers, no shuffles. Replaces r11-measured
// 150.5us / MfmaUtil 20% / 11 serial lgkmcnt(0) drains / 36 LDS ops/layer.
// ---------------------------------------------------------------------------
#define MFMA16 __builtin_amdgcn_mfma_f32_16x16x16f16

template<int KC, bool RELU>
__device__ __forceinline__ void layerx(const f16x4* __restrict__ Wt,
                                       const f16x4 Xin[2][8], f16x4 Xout[2][8],
                                       int lane) {
#pragma unroll
    for (int ct = 0; ct < 4; ct++) {
        f32x4 acc0 = {0.f,0.f,0.f,0.f}, acc1 = {0.f,0.f,0.f,0.f};
#pragma unroll
        for (int kc = 0; kc < KC; kc++) {
            f16x4 w = Wt[(ct*KC + kc)*64 + lane];
            acc0 = MFMA16(w, Xin[0][kc], acc0, 0, 0, 0);
            acc1 = MFMA16(w, Xin[1][kc], acc1, 0, 0, 0);
        }
        f16x4 o0, o1;
#pragma unroll
        for (int i = 0; i < 4; i++) {
            float v0 = acc0[i], v1 = acc1[i];
            if (RELU) { v0 = fmaxf(v0, 0.f); v1 = fmaxf(v1, 0.f); }
            o0[i] = (_Float16)v0; o1[i] = (_Float16)v1;
        }
        Xout[0][ct] = o0; Xout[1][ct] = o1;
    }
}

__device__ __forceinline__ void load_enc16(const uint32_t* __restrict__ Enc,
                                           int pbase, int m, int q,
                                           f16x4 X[2][8]) {
#pragma unroll
    for (int rt = 0; rt < 2; rt++) {
        int p = pbase + rt*16 + m;
#pragma unroll
        for (int kc = 0; kc < 2; kc++) {
            PackF16 a, b;
            a.u = Enc[(size_t)(kc*8 + q*2 + 0) * NPTS + p];
            b.u = Enc[(size_t)(kc*8 + q*2 + 1) * NPTS + p];
            f16x4 v;
            v[0] = a.h[0]; v[1] = a.h[1]; v[2] = b.h[0]; v[3] = b.h[1];
            X[rt][kc] = v;
        }
    }
}

__launch_bounds__(256, 4)
__global__ void k_mlp(const uint32_t* __restrict__ EncS, const uint32_t* __restrict__ EncD,
                      const _Float16* __restrict__ Wfrag, const float* __restrict__ alphap,
                      const float* __restrict__ w2out, float* __restrict__ out) {
    int tid  = threadIdx.x;
    int wave = tid >> 6, lane = tid & 63;
    int m = lane & 15, q = lane >> 4;
    int pbase = blockIdx.x * 128 + wave * 32;
    const f16x4* W4 = (const f16x4*)Wfrag;
    float alpha = alphap[0];

    f16x4 T1[2][8], T2[2][8], Ys[2][8], Yd[2][8];

    // ---- dynamic encoder chain (bases +72) ----
    load_enc16(EncD, pbase, m, q, T1);
    layerx<2, true >(W4 +  72*64, T1, T2, lane);
    layerx<4, true >(W4 +  80*64, T2, T1, lane);
    layerx<4, true >(W4 +  96*64, T1, T2, lane);
    layerx<4, true >(W4 + 112*64, T2, T1, lane);
    layerx<4, false>(W4 + 128*64, T1, Yd, lane);   // linear out -> Yd[.][0..3]
    // ---- static encoder chain ----
    load_enc16(EncS, pbase, m, q, T1);
    layerx<2, true >(W4 +   0*64, T1, T2, lane);
    layerx<4, true >(W4 +   8*64, T2, T1, lane);
    layerx<4, true >(W4 +  24*64, T1, T2, lane);
    layerx<4, true >(W4 +  40*64, T2, T1, lane);
    layerx<4, false>(W4 +  56*64, T1, Ys, lane);   // linear out -> Ys[.][0..3]
    // ---- mlp1 layer 1: 128->64 relu (K = Ys||Yd) ----
#pragma unroll
    for (int ct = 0; ct < 4; ct++) {
        f32x4 acc0 = {0.f,0.f,0.f,0.f}, acc1 = {0.f,0.f,0.f,0.f};
#pragma unroll
        for (int kc = 0; kc < 8; kc++) {
            f16x4 w  = W4[(144 + ct*8 + kc)*64 + lane];
            f16x4 x0 = (kc < 4) ? Ys[0][kc] : Yd[0][kc-4];
            f16x4 x1 = (kc < 4) ? Ys[1][kc] : Yd[1][kc-4];
            acc0 = MFMA16(w, x0, acc0, 0, 0, 0);
            acc1 = MFMA16(w, x1, acc1, 0, 0, 0);
        }
        f16x4 o0, o1;
#pragma unroll
        for (int i = 0; i < 4; i++) {
            o0[i] = (_Float16)fmaxf(acc0[i], 0.f);
            o1[i] = (_Float16)fmaxf(acc1[i], 0.f);
        }
        T1[0][ct] = o0; T1[1][ct] = o1;
    }
    // ---- mlp1 layer 2: 64->64 relu ----
    layerx<4, true>(W4 + 176*64, T1, T2, lane);
    // ---- out1 (64->128) + skip blend -> T1[.][0..7] (128 feats) ----
#pragma unroll
    for (int h2 = 0; h2 < 2; h2++) {
#pragma unroll
        for (int ct = 0; ct < 4; ct++) {
            f32x4 acc0 = {0.f,0.f,0.f,0.f}, acc1 = {0.f,0.f,0.f,0.f};
#pragma unroll
            for (int kc = 0; kc < 4; kc++) {
                f16x4 w = W4[(192 + (h2*4+ct)*4 + kc)*64 + lane];
                acc0 = MFMA16(w, T2[0][kc], acc0, 0, 0, 0);
                acc1 = MFMA16(w, T2[1][kc], acc1, 0, 0, 0);
            }
            f16x4 s0 = h2 ? Yd[0][ct] : Ys[0][ct];
            f16x4 s1 = h2 ? Yd[1][ct] : Ys[1][ct];
            f16x4 o0, o1;
#pragma unroll
            for (int i = 0; i < 4; i++) {
                o0[i] = (_Float16)(alpha*acc0[i] + (1.f-alpha)*(float)s0[i]);
                o1[i] = (_Float16)(alpha*acc1[i] + (1.f-alpha)*(float)s1[i]);
            }
            T1[0][h2*4+ct] = o0; T1[1][h2*4+ct] = o1;
        }
    }
    // ---- mlp2 layer 1: 128->64 relu ----
#pragma unroll
    for (int ct = 0; ct < 4; ct++) {
        f32x4 acc0 = {0.f,0.f,0.f,0.f}, acc1 = {0.f,0.f,0.f,0.f};
#pragma unroll
        for (int kc = 0; kc < 8; kc++) {
            f16x4 w = W4[(224 + ct*8 + kc)*64 + lane];
            acc0 = MFMA16(w, T1[0][kc], acc0, 0, 0, 0);
            acc1 = MFMA16(w, T1[1][kc], acc1, 0, 0, 0);
        }
        f16x4 o0, o1;
#pragma unroll
        for (int i = 0; i < 4; i++) {
            o0[i] = (_Float16)fmaxf(acc0[i], 0.f);
            o1[i] = (_Float16)fmaxf(acc1[i], 0.f);
        }
        T2[0][ct] = o0; T2[1][ct] = o1;
    }
    // ---- mlp2 layer 2 (64->64) + relu + dot(w2out) fused ----
    float rs0 = 0.f, rs1 = 0.f;
#pragma unroll
    for (int ct = 0; ct < 4; ct++) {
        f32x4 acc0 = {0.f,0.f,0.f,0.f}, acc1 = {0.f,0.f,0.f,0.f};
#pragma unroll
        for (int kc = 0; kc < 4; kc++) {
            f16x4 w = W4[(256 + ct*4 + kc)*64 + lane];
            acc0 = MFMA16(w, T2[0][kc], acc0, 0, 0, 0);
            acc1 = MFMA16(w, T2[1][kc], acc1, 0, 0, 0);
        }
        float4 wv = *(const float4*)(w2out + ct*16 + q*4);
        const float* wvp = (const float*)&wv;
#pragma unroll
        for (int i = 0; i < 4; i++) {
            rs0 += fmaxf(acc0[i], 0.f) * wvp[i];
            rs1 += fmaxf(acc1[i], 0.f) * wvp[i];
        }
    }
    // sum over quads (feature dim spans q): lanes {m, m+16, m+32, m+48}
    rs0 += __shfl_xor(rs0, 16, 64); rs0 += __shfl_xor(rs0, 32, 64);
    rs1 += __shfl_xor(rs1, 16, 64); rs1 += __shfl_xor(rs1, 32, 64);
    if (q == 0) {
        out[pbase +  0 + m] = rs0;
        out[pbase + 16 + m] = rs1;
    }
}

// ---------------------------------------------------------------------------
extern "C" void kernel_launch(void* const* d_in, const int* in_sizes, int n_in,
                              void* d_out, int out_size, void* d_ws, size_t ws_size,
                              hipStream_t stream) {
    const float* x      = (const float*)d_in[0];
    const float* t      = (const float*)d_in[1];
    const float* alpha  = (const float*)d_in[2];
    const float* tab_s  = (const float*)d_in[3];
    const float* ws_in  = (const float*)d_in[4];
    const float* ws_hid = (const float*)d_in[5];
    const float* ws_out = (const float*)d_in[6];
    const float* tab_d  = (const float*)d_in[7];
    const float* wd_in  = (const float*)d_in[8];
    const float* wd_hid = (const float*)d_in[9];
    const float* wd_out = (const float*)d_in[10];
    const float* w1_in  = (const float*)d_in[11];
    const float* w1_hid = (const float*)d_in[12];
    const float* w1_out = (const float*)d_in[13];
    const float* w2_in  = (const float*)d_in[14];
    const float* w2_hid = (const float*)d_in[15];
    const float* w2_out = (const float*)d_in[16];
    float* out = (float*)d_out;

    char* ws = (char*)d_ws;
    _Float16* Wfrag = (_Float16*)ws;                       // 139264 B
    uint2*    Tc    = (uint2*)(ws + 139264);               // 64 MiB combined table
    uint32_t* EncS  = (uint32_t*)(ws + 139264 + 67108864); // 32 MiB [lvl][pt]
    uint32_t* EncD  = EncS + (size_t)LVLS * NPTS;          // 32 MiB [lvl][pt]
    size_t needed = 139264 + 67108864 + 2ull * 33554432ull;
    if (ws_size < needed) return;

    WPtrs wp;
    wp.p[0] = ws_in;  wp.p[1] = ws_hid; wp.p[2] = ws_out;
    wp.p[3] = wd_in;  wp.p[4] = wd_hid; wp.p[5] = wd_out;
    wp.p[6] = w1_in;  wp.p[7] = w1_hid; wp.p[8] = w1_out;
    wp.p[9] = w2_in;  wp.p[10] = w2_hid;

    k_build  <<<10308, 256, 0, stream>>>(tab_s, tab_d, t, Tc, wp, Wfrag);
    k_encode <<<4096,  256, 0, stream>>>(x, Tc, EncS, EncD);
    k_mlp    <<<NPTS/128, 256, 0, stream>>>(EncS, EncD, Wfrag, alpha, w2_out, out);
}